// Round 4
// baseline (360.796 us; speedup 1.0000x reference)
//
#include <hip/hip_runtime.h>

// ---------------------------------------------------------------------------
// GConvLSTM cell, B=4, N=4096, CI=CO=32, K=3.
//
// R3: runtime dtype detection. The reference declares float32; prior rounds
// assumed the harness bf16-ified everything and always NaN'd (Inf from
// f32-mantissa words read as bf16 survives NaN-scrub and poisons MFMA).
// flag_k inspects L's bit patterns and sets mode: 0 = bf16 buffers,
// 1 = f32 buffers. All external loads/stores branch on mode; internal
// workspace tensors are always bf16.
//
// Pipeline:
//   0) flag_k:  detect dtype -> ws flag
//   1) pack:  M0T[256][4096] = [X|H]^T (k-contig), WcatT[128][192], biases
//   2) gemm mode0:  Y1 = L @ M0 -> Y1N[4096][256] + Y1T[256][4096] (bf16)
//   3) gemm mode1:  T2 = 2*(L @ Y1) - M0 -> T2N[4096][256] (bf16)
//   4) combine: feats {X,T1x,T2x,H,T1h,T2h} @ WcatT -> gates -> H_new,C_new
// ---------------------------------------------------------------------------

typedef __bf16 bf16x8 __attribute__((ext_vector_type(8)));
typedef float f32x4 __attribute__((ext_vector_type(4)));

typedef unsigned short u16;
typedef unsigned int u32;

__device__ __forceinline__ float b2f(u16 h) {
  u32 u = ((u32)h) << 16;
  return __builtin_bit_cast(float, u);
}
__device__ __forceinline__ u16 f2b(float f) {
  u32 u = __builtin_bit_cast(u32, f);
  u += 0x7fffu + ((u >> 16) & 1u);   // round-to-nearest-even
  return (u16)(u >> 16);
}
__device__ __forceinline__ u16 scrub16(u16 h) {            // NaN bf16 -> 0
  return ((u16)(h & 0x7fffu) > (u16)0x7f80u) ? (u16)0 : h;
}
__device__ __forceinline__ float scrubf(float f) { return (f == f) ? f : 0.0f; }
__device__ __forceinline__ float sigm(float x) { return 1.0f / (1.0f + __expf(-x)); }
__device__ __forceinline__ float tanh_f(float x) { return 1.0f - 2.0f / (__expf(2.0f * x) + 1.0f); }

// ---------------------------------------------------------------------------
// Workspace layout (bytes) — total ~8.05 MB
// ---------------------------------------------------------------------------
#define WS_M0T   0u          // [256][4096] u16, 2 MB
#define WS_Y1T   2097152u    // [256][4096] u16, 2 MB
#define WS_Y1N   4194304u    // [4096][256] u16, 2 MB
#define WS_T2N   6291456u    // [4096][256] u16, 2 MB
#define WS_WCAT  8388608u    // [128][192] u16, 48 KB
#define WS_GB    8437760u    // [4][32] f32
#define WS_WC    8438272u    // [3][32] f32
#define WS_FLAG  8438784u    // u32: 0 = bf16 inputs, 1 = f32 inputs

// ---------------------------------------------------------------------------
// dtype-detect kernel: scan first 1024 u16 words of L.
// bf16 data (sigma=1/64): exponent field in [96,126] for ~100% of words.
// f32 data read as u16: odd words pass (~100%), even mantissa words ~12%.
// ---------------------------------------------------------------------------
__global__ __launch_bounds__(64) void flag_k(const u16* __restrict__ L,
                                             u32* __restrict__ flag) {
  __shared__ int cnt;
  if (threadIdx.x == 0) cnt = 0;
  __syncthreads();
  int c = 0;
  for (int i = threadIdx.x; i < 1024; i += 64) {
    int e = (L[i] >> 7) & 0xFF;
    if (e >= 96 && e <= 126) ++c;
  }
  atomicAdd(&cnt, c);
  __syncthreads();
  if (threadIdx.x == 0) *flag = (cnt < 870) ? 1u : 0u;
}

// ---------------------------------------------------------------------------
// pack kernel
// ---------------------------------------------------------------------------
struct PackArgs {
  const void* in[27];
  u16* m0t;     // [256][4096]
  u16* wcat;    // [128][192]
  float* gb;    // [4][32]  (I,F,T,O) = bx+bh+b_
  float* wc;    // [3][32]  (w_ci, w_cf, w_co)
  const u32* flag;
};

__device__ __forceinline__ float rd_elem(const void* p, size_t idx, u32 mode) {
  return mode ? ((const float*)p)[idx] : b2f(((const u16*)p)[idx]);
}

__global__ __launch_bounds__(256) void pack_k(PackArgs pa) {
  const int bid = blockIdx.x;
  const int t = threadIdx.x;
  const u32 mode = *pa.flag;
  __shared__ u32 lds[256][17];

  if (bid < 128) {
    // transpose one (tensor, batch, 256-node chunk): X/H [4096][32] -> M0T rows
    const int ts = bid >> 4, nc = bid & 15;
    const int xh = ts >> 2, b = ts & 3;
    const void* src = pa.in[xh ? 2 : 0];
    const int node = nc * 256 + t;
    const size_t rbase = ((size_t)b * 4096 + node) * 32;
    if (mode) {
      const f32x4* s4 = (const f32x4*)((const float*)src + rbase);
      u16 tv[32];
      #pragma unroll
      for (int j = 0; j < 8; ++j) {
        f32x4 v = s4[j];
        tv[j * 4] = f2b(v[0]); tv[j * 4 + 1] = f2b(v[1]);
        tv[j * 4 + 2] = f2b(v[2]); tv[j * 4 + 3] = f2b(v[3]);
      }
      #pragma unroll
      for (int i = 0; i < 16; ++i)
        lds[t][i] = (u32)tv[2 * i] | ((u32)tv[2 * i + 1] << 16);
    } else {
      const uint4* s4 = (const uint4*)((const u16*)src + rbase);
      uint4 q0 = s4[0], q1 = s4[1], q2 = s4[2], q3 = s4[3];
      lds[t][0] = q0.x;  lds[t][1] = q0.y;  lds[t][2] = q0.z;  lds[t][3] = q0.w;
      lds[t][4] = q1.x;  lds[t][5] = q1.y;  lds[t][6] = q1.z;  lds[t][7] = q1.w;
      lds[t][8] = q2.x;  lds[t][9] = q2.y;  lds[t][10] = q2.z; lds[t][11] = q2.w;
      lds[t][12] = q3.x; lds[t][13] = q3.y; lds[t][14] = q3.z; lds[t][15] = q3.w;
    }
    __syncthreads();
    const int f = t & 31, sc = t >> 5;           // feature, node-subchunk
    const int ccol = xh * 128 + b * 32 + f;
    u16 tmp[32];
    #pragma unroll
    for (int i = 0; i < 32; ++i) {
      u32 wv = lds[sc * 32 + i][f >> 1];
      tmp[i] = scrub16((f & 1) ? (u16)(wv >> 16) : (u16)(wv & 0xffffu));
    }
    u16* dst = pa.m0t + (size_t)ccol * 4096 + nc * 256 + sc * 32;
    #pragma unroll
    for (int i = 0; i < 32; i += 8)
      *(uint4*)&dst[i] = *(const uint4*)&tmp[i];
  } else if (bid == 128) {
    // WcatT[col][j]: col = g*32+o ; j = a*32+jj ; a<3 -> Wx_g[a][jj][o] else Wh_g
    const int wxi[4] = {4, 8, 12, 16};
    const int whi[4] = {6, 10, 14, 18};
    for (int e = t; e < 24576; e += 256) {
      int col = e / 192, j = e % 192;
      int g = col >> 5, o = col & 31;
      int a = j >> 5, jj = j & 31;
      const void* Wsrc = (a < 3) ? pa.in[wxi[g]] : pa.in[whi[g]];
      int k = (a < 3) ? a : (a - 3);
      pa.wcat[e] = scrub16(f2b(rd_elem(Wsrc, k * 1024 + jj * 32 + o, mode)));
    }
  } else {
    // biases + peepholes
    if (t < 128) {
      const int bx[4] = {5, 9, 13, 17}, bh[4] = {7, 11, 15, 19}, bb[4] = {23, 24, 25, 26};
      int g = t >> 5, o = t & 31;
      pa.gb[t] = scrubf(rd_elem(pa.in[bx[g]], o, mode) + rd_elem(pa.in[bh[g]], o, mode) +
                        rd_elem(pa.in[bb[g]], o, mode));
    } else if (t < 224) {
      int j = t - 128;
      int which = j >> 5, o = j & 31;
      pa.wc[j] = scrubf(rd_elem(pa.in[20 + which], o, mode));
    }
  }
}

// ---------------------------------------------------------------------------
// GEMM: out[m][c] = sum_k A[m][k] * B[c][k]   (A=L [4096][4096], B [256][4096])
// grid = 64 rowTiles * 4 colTiles = 256 blocks, 256 threads (4 waves 2x2).
// Block tile 64x64, BK=64; wave tile 32x32 via 2x2 mfma_f32_16x16x32_bf16.
// A (=L, external) staging converts f32->bf16 when mode==1. B is internal bf16.
// mode0: write Y1 bf16 to outN[m][c] and outT[c][m]
// mode1: write T2 = 2*acc - M0T[c][m] bf16 to outN[m][c]
// ---------------------------------------------------------------------------
#define LDS_STRIDE 72

__global__ __launch_bounds__(256) void gemm_k(const void* __restrict__ A,
                                              const u16* __restrict__ B,
                                              const u16* __restrict__ M0T,
                                              u16* __restrict__ outN,
                                              u16* __restrict__ outT,
                                              const u32* __restrict__ flag,
                                              const int emode) {
  __shared__ __align__(16) u16 ldsA[64 * LDS_STRIDE];
  __shared__ __align__(16) u16 ldsB[64 * LDS_STRIDE];
  const int tid = threadIdx.x;
  const int l = tid & 63;
  const int w = tid >> 6;
  const int colTile = blockIdx.x & 3;
  const int rowTile = blockIdx.x >> 2;
  const int wRow = w >> 1, wCol = w & 1;
  const u32 mode = *flag;

  f32x4 acc[4];
  #pragma unroll
  for (int i = 0; i < 4; ++i)
    #pragma unroll
    for (int e = 0; e < 4; ++e) acc[i][e] = 0.0f;

  const size_t Aoff = (size_t)(rowTile * 64) * 4096;
  const u16* Bbase = B + (size_t)(colTile * 64) * 4096;

  const int srow = tid >> 2;          // 0..63
  const int sch = (tid & 3) * 2;      // chunk pair (2 x 16B) within 128B bf16 row

  for (int it = 0; it < 64; ++it) {
    const int kOff = it * 64;
    const size_t aidx = Aoff + (size_t)srow * 4096 + kOff + sch * 8;
    if (mode) {
      const float* Af = (const float*)A + aidx;
      u16 tv[16];
      #pragma unroll
      for (int q = 0; q < 4; ++q) {
        f32x4 v = *(const f32x4*)(Af + q * 4);
        tv[q * 4] = f2b(v[0]); tv[q * 4 + 1] = f2b(v[1]);
        tv[q * 4 + 2] = f2b(v[2]); tv[q * 4 + 3] = f2b(v[3]);
      }
      *(uint4*)&ldsA[srow * LDS_STRIDE + sch * 8] = ((const uint4*)tv)[0];
      *(uint4*)&ldsA[srow * LDS_STRIDE + sch * 8 + 8] = ((const uint4*)tv)[1];
    } else {
      const u16* ga = (const u16*)A + aidx;
      *(uint4*)&ldsA[srow * LDS_STRIDE + sch * 8] = *(const uint4*)ga;
      *(uint4*)&ldsA[srow * LDS_STRIDE + sch * 8 + 8] = *(const uint4*)(ga + 8);
    }
    const u16* gb = Bbase + (size_t)srow * 4096 + kOff + sch * 8;
    *(uint4*)&ldsB[srow * LDS_STRIDE + sch * 8] = *(const uint4*)gb;
    *(uint4*)&ldsB[srow * LDS_STRIDE + sch * 8 + 8] = *(const uint4*)(gb + 8);
    __syncthreads();
    #pragma unroll
    for (int kstep = 0; kstep < 2; ++kstep) {
      const int kb = kstep * 32 + (l >> 4) * 8;   // frag: k = quad*8 + j
      bf16x8 af[2], bf[2];
      #pragma unroll
      for (int mt = 0; mt < 2; ++mt)
        af[mt] = *(const bf16x8*)&ldsA[(wRow * 32 + mt * 16 + (l & 15)) * LDS_STRIDE + kb];
      #pragma unroll
      for (int nt = 0; nt < 2; ++nt)
        bf[nt] = *(const bf16x8*)&ldsB[(wCol * 32 + nt * 16 + (l & 15)) * LDS_STRIDE + kb];
      #pragma unroll
      for (int mt = 0; mt < 2; ++mt)
        #pragma unroll
        for (int nt = 0; nt < 2; ++nt)
          acc[mt * 2 + nt] =
              __builtin_amdgcn_mfma_f32_16x16x32_bf16(af[mt], bf[nt], acc[mt * 2 + nt], 0, 0, 0);
    }
    __syncthreads();
  }

  // epilogue: C/D layout col = lane&15, row = (lane>>4)*4 + reg
  if (emode == 0) {
    #pragma unroll
    for (int mt = 0; mt < 2; ++mt) {
      const int mBase = rowTile * 64 + wRow * 32 + mt * 16 + (l >> 4) * 4;
      #pragma unroll
      for (int nt = 0; nt < 2; ++nt) {
        const int c = colTile * 64 + wCol * 32 + nt * 16 + (l & 15);
        f32x4 v = acc[mt * 2 + nt];
        #pragma unroll
        for (int reg = 0; reg < 4; ++reg) {
          const int m = mBase + reg;
          const u16 h = f2b(scrubf(v[reg]));
          outN[(size_t)m * 256 + c] = h;
          outT[(size_t)c * 4096 + m] = h;
        }
      }
    }
  } else {
    #pragma unroll
    for (int mt = 0; mt < 2; ++mt) {
      const int mBase = rowTile * 64 + wRow * 32 + mt * 16 + (l >> 4) * 4;
      #pragma unroll
      for (int nt = 0; nt < 2; ++nt) {
        const int c = colTile * 64 + wCol * 32 + nt * 16 + (l & 15);
        f32x4 v = acc[mt * 2 + nt];
        #pragma unroll
        for (int reg = 0; reg < 4; ++reg) {
          const int m = mBase + reg;
          const float t0 = b2f(M0T[(size_t)c * 4096 + m]);
          outN[(size_t)m * 256 + c] = f2b(scrubf(2.0f * v[reg] - t0));
        }
      }
    }
  }
}

// ---------------------------------------------------------------------------
// combine: per (b,n) row build 192 feats, GEMM vs WcatT, gate epilogue
// grid 256 blocks (64 rows each) x 256 threads (4 waves, 16 rows/wave)
// ---------------------------------------------------------------------------
struct CombArgs {
  const void* X; const void* H; const void* C;
  const u16* Y1N; const u16* T2N;
  const u16* WCAT; const float* GB; const float* WC;
  void* OUT;
  const u32* flag;
};

__global__ __launch_bounds__(256) void combine_k(CombArgs a) {
  __shared__ __align__(16) u16 feat[64][200];
  const int t = threadIdx.x;
  const int l = t & 63;
  const int w = t >> 6;
  const int R0 = blockIdx.x * 64;
  const u32 mode = *a.flag;

  {
    const int R = R0 + l;
    const int b = R >> 12, n = R & 4095;
    if (w == 0) {
      if (mode) {
        const f32x4* xs = (const f32x4*)((const float*)a.X + (size_t)R * 32);
        const f32x4* hs = (const f32x4*)((const float*)a.H + (size_t)R * 32);
        u16 tx[32], th[32];
        #pragma unroll
        for (int j = 0; j < 8; ++j) {
          f32x4 vx = xs[j], vh = hs[j];
          tx[j * 4] = f2b(vx[0]); tx[j * 4 + 1] = f2b(vx[1]);
          tx[j * 4 + 2] = f2b(vx[2]); tx[j * 4 + 3] = f2b(vx[3]);
          th[j * 4] = f2b(vh[0]); th[j * 4 + 1] = f2b(vh[1]);
          th[j * 4 + 2] = f2b(vh[2]); th[j * 4 + 3] = f2b(vh[3]);
        }
        #pragma unroll
        for (int i = 0; i < 32; i += 8) {
          *(uint4*)&feat[l][i] = *(const uint4*)&tx[i];
          *(uint4*)&feat[l][96 + i] = *(const uint4*)&th[i];
        }
      } else {
        const uint4* xs = (const uint4*)((const u16*)a.X + (size_t)R * 32);
        *(uint4*)&feat[l][0] = xs[0];  *(uint4*)&feat[l][8] = xs[1];
        *(uint4*)&feat[l][16] = xs[2]; *(uint4*)&feat[l][24] = xs[3];
        const uint4* hs = (const uint4*)((const u16*)a.H + (size_t)R * 32);
        *(uint4*)&feat[l][96] = hs[0];  *(uint4*)&feat[l][104] = hs[1];
        *(uint4*)&feat[l][112] = hs[2]; *(uint4*)&feat[l][120] = hs[3];
      }
    } else if (w == 1) {
      const uint4* t1 = (const uint4*)(a.Y1N + (size_t)n * 256 + b * 32);
      *(uint4*)&feat[l][32] = t1[0]; *(uint4*)&feat[l][40] = t1[1];
      *(uint4*)&feat[l][48] = t1[2]; *(uint4*)&feat[l][56] = t1[3];
      const uint4* t1h = (const uint4*)(a.Y1N + (size_t)n * 256 + 128 + b * 32);
      *(uint4*)&feat[l][128] = t1h[0]; *(uint4*)&feat[l][136] = t1h[1];
      *(uint4*)&feat[l][144] = t1h[2]; *(uint4*)&feat[l][152] = t1h[3];
    } else if (w == 2) {
      const uint4* t2 = (const uint4*)(a.T2N + (size_t)n * 256 + b * 32);
      *(uint4*)&feat[l][64] = t2[0]; *(uint4*)&feat[l][72] = t2[1];
      *(uint4*)&feat[l][80] = t2[2]; *(uint4*)&feat[l][88] = t2[3];
      const uint4* t2h = (const uint4*)(a.T2N + (size_t)n * 256 + 128 + b * 32);
      *(uint4*)&feat[l][160] = t2h[0]; *(uint4*)&feat[l][168] = t2h[1];
      *(uint4*)&feat[l][176] = t2h[2]; *(uint4*)&feat[l][184] = t2h[3];
    }
  }
  __syncthreads();
  // scrub feats (identity on clean data)
  {
    const int row = t >> 2, c0 = (t & 3) * 48;
    #pragma unroll
    for (int i = 0; i < 48; ++i) feat[row][c0 + i] = scrub16(feat[row][c0 + i]);
  }
  __syncthreads();

  f32x4 acc[8];
  #pragma unroll
  for (int i = 0; i < 8; ++i)
    #pragma unroll
    for (int e = 0; e < 4; ++e) acc[i][e] = 0.0f;

  const int rowB = w * 16;
  #pragma unroll
  for (int ks = 0; ks < 6; ++ks) {
    bf16x8 af = *(const bf16x8*)&feat[rowB + (l & 15)][(l >> 4) * 8 + ks * 32];
    #pragma unroll
    for (int ct = 0; ct < 8; ++ct) {
      int ncol = ct * 16 + (l & 15);
      bf16x8 bv = *(const bf16x8*)&a.WCAT[(size_t)ncol * 192 + (l >> 4) * 8 + ks * 32];
      acc[ct] = __builtin_amdgcn_mfma_f32_16x16x32_bf16(af, bv, acc[ct], 0, 0, 0);
    }
  }

  const int o16 = l & 15;
  const int rq = (l >> 4) * 4;
  #pragma unroll
  for (int ctp = 0; ctp < 2; ++ctp) {
    const int o = ctp * 16 + o16;
    const float gbI = a.GB[o], gbF = a.GB[32 + o], gbT = a.GB[64 + o], gbO = a.GB[96 + o];
    const float wci = a.WC[o], wcf = a.WC[32 + o], wco = a.WC[64 + o];
    #pragma unroll
    for (int i = 0; i < 4; ++i) {
      const int R = R0 + w * 16 + rq + i;
      const size_t oidx = (size_t)R * 32 + o;
      const float cold = scrubf(mode ? ((const float*)a.C)[oidx]
                                     : b2f(((const u16*)a.C)[oidx]));
      const float vI = acc[0 + ctp][i] + gbI + wci * cold;
      const float vF = acc[2 + ctp][i] + gbF + wcf * cold;
      const float vT = acc[4 + ctp][i] + gbT;
      const float vO = acc[6 + ctp][i] + gbO;
      const float I = sigm(vI);
      const float F = sigm(vF);
      const float T = tanh_f(vT);
      const float Cn = F * cold + I * T;
      const float O = sigm(vO + wco * Cn);
      const float Hn = O * tanh_f(Cn);
      if (mode) {
        ((float*)a.OUT)[oidx] = Hn;
        ((float*)a.OUT)[524288 + oidx] = Cn;
      } else {
        ((u16*)a.OUT)[oidx] = f2b(Hn);
        ((u16*)a.OUT)[524288 + oidx] = f2b(Cn);
      }
    }
  }
}

// ---------------------------------------------------------------------------
// launcher
// ---------------------------------------------------------------------------
extern "C" void kernel_launch(void* const* d_in, const int* in_sizes, int n_in,
                              void* d_out, int out_size, void* d_ws, size_t ws_size,
                              hipStream_t stream) {
  char* ws = (char*)d_ws;
  u16* M0T = (u16*)(ws + WS_M0T);
  u16* Y1T = (u16*)(ws + WS_Y1T);
  u16* Y1N = (u16*)(ws + WS_Y1N);
  u16* T2N = (u16*)(ws + WS_T2N);
  u16* WCAT = (u16*)(ws + WS_WCAT);
  float* GB = (float*)(ws + WS_GB);
  float* WC = (float*)(ws + WS_WC);
  u32* FLAG = (u32*)(ws + WS_FLAG);

  flag_k<<<1, 64, 0, stream>>>((const u16*)d_in[1], FLAG);

  PackArgs pa;
  for (int i = 0; i < 27; ++i) pa.in[i] = d_in[i];
  pa.m0t = M0T; pa.wcat = WCAT; pa.gb = GB; pa.wc = WC; pa.flag = FLAG;
  pack_k<<<130, 256, 0, stream>>>(pa);

  gemm_k<<<256, 256, 0, stream>>>(d_in[1], M0T, nullptr, Y1N, Y1T, FLAG, 0);
  gemm_k<<<256, 256, 0, stream>>>(d_in[1], Y1T, M0T, T2N, nullptr, FLAG, 1);

  CombArgs ca;
  ca.X = d_in[0];
  ca.H = d_in[2];
  ca.C = d_in[3];
  ca.Y1N = Y1N; ca.T2N = T2N; ca.WCAT = WCAT; ca.GB = GB; ca.WC = WC;
  ca.OUT = d_out;
  ca.flag = FLAG;
  combine_k<<<256, 256, 0, stream>>>(ca);
}

// Round 5
// 260.521 us; speedup vs baseline: 1.3849x; 1.3849x over previous
//
#include <hip/hip_runtime.h>

// ---------------------------------------------------------------------------
// GConvLSTM cell, B=4, N=4096, CI=CO=32, K=3.  Inputs/outputs f32 (runtime-
// detected via flag_k; bf16 fallback retained).  Internal compute bf16 MFMA.
//
// R5 fast path (ws >= 58.7 MB):
//   0) flag_k:   detect input dtype
//   1) convL_k:  L f32 -> Lbf bf16 [4096][4096] (both gemms reuse)
//   2) pack_k:   M0T[256][4096] = [X|H]^T, WcatT[128][192], biases
//   3) gemm_k:   PART[4][4096][256] f32 = split-K(4) partials of L @ M0
//                (1024 blocks = 4/CU, global_load_lds w16 + XOR swizzle)
//   4) reduce_k: Y1N[4096][256] + Y1T[256][4096] bf16 = sum partials
//   5) gemm_k:   PART = split-K partials of L @ Y1
//   6) combine_k: feats {X,T1x,T2x,H,T1h,T2h} @ WcatT -> gates -> H,C
//                (T2 = 2*sum(PART) - M0 fused in)
// Fallback path (ws < 58.7 MB): R4's proven 256-block gemm pipeline.
// ---------------------------------------------------------------------------

typedef __bf16 bf16x8 __attribute__((ext_vector_type(8)));
typedef float f32x4 __attribute__((ext_vector_type(4)));

typedef unsigned short u16;
typedef unsigned int u32;

__device__ __forceinline__ float b2f(u16 h) {
  u32 u = ((u32)h) << 16;
  return __builtin_bit_cast(float, u);
}
__device__ __forceinline__ u16 f2b(float f) {
  u32 u = __builtin_bit_cast(u32, f);
  u += 0x7fffu + ((u >> 16) & 1u);   // round-to-nearest-even
  return (u16)(u >> 16);
}
__device__ __forceinline__ u16 scrub16(u16 h) {
  return ((u16)(h & 0x7fffu) > (u16)0x7f80u) ? (u16)0 : h;
}
__device__ __forceinline__ float scrubf(float f) { return (f == f) ? f : 0.0f; }
__device__ __forceinline__ float sigm(float x) { return 1.0f / (1.0f + __expf(-x)); }
__device__ __forceinline__ float tanh_f(float x) { return 1.0f - 2.0f / (__expf(2.0f * x) + 1.0f); }

#define AS1 __attribute__((address_space(1)))
#define AS3 __attribute__((address_space(3)))
__device__ __forceinline__ void ld_lds16(const void* g, void* l) {
  __builtin_amdgcn_global_load_lds((const AS1 void*)g, (AS3 void*)l, 16, 0, 0);
}

// ---------------------------------------------------------------------------
// Workspace layouts (bytes).  FAST and FB layouts are mutually exclusive.
// ---------------------------------------------------------------------------
// fast path
#define FWS_M0T   0u          // [256][4096] u16, 2 MB
#define FWS_Y1T   2097152u    // [256][4096] u16, 2 MB
#define FWS_Y1N   4194304u    // [4096][256] u16, 2 MB
#define FWS_WCAT  6291456u    // [128][192] u16
#define FWS_GB    6340608u
#define FWS_WC    6341120u
#define FWS_FLAG  6341632u
#define FWS_LBF   8388608u    // [4096][4096] u16, 32 MB
#define FWS_PART  41943040u   // [4][4096][256] f32, 16 MB
#define FWS_TOTAL 58720256u
// fallback (R4) layout
#define BWS_M0T   0u
#define BWS_Y1T   2097152u
#define BWS_Y1N   4194304u
#define BWS_T2N   6291456u
#define BWS_WCAT  8388608u
#define BWS_GB    8437760u
#define BWS_WC    8438272u
#define BWS_FLAG  8438784u

// ---------------------------------------------------------------------------
// dtype-detect: scan first 1024 u16 words of L.
// ---------------------------------------------------------------------------
__global__ __launch_bounds__(64) void flag_k(const u16* __restrict__ L,
                                             u32* __restrict__ flag) {
  __shared__ int cnt;
  if (threadIdx.x == 0) cnt = 0;
  __syncthreads();
  int c = 0;
  for (int i = threadIdx.x; i < 1024; i += 64) {
    int e = (L[i] >> 7) & 0xFF;
    if (e >= 96 && e <= 126) ++c;
  }
  atomicAdd(&cnt, c);
  __syncthreads();
  if (threadIdx.x == 0) *flag = (cnt < 870) ? 1u : 0u;
}

// ---------------------------------------------------------------------------
// convL: L (f32 or bf16) -> Lbf bf16.  16.7M elems, 4/thread, coalesced.
// grid 16384 blocks? no: 524288 threads x 8 iters x 4 elems.
// ---------------------------------------------------------------------------
__global__ __launch_bounds__(256) void convL_k(const void* __restrict__ L,
                                               u16* __restrict__ Lbf,
                                               const u32* __restrict__ flag) {
  const u32 mode = *flag;
  const int gtid = blockIdx.x * 256 + threadIdx.x;     // 0..524287
  #pragma unroll
  for (int it = 0; it < 8; ++it) {
    const size_t e0 = ((size_t)it * 524288 + gtid) * 4;
    if (mode) {
      f32x4 v = *(const f32x4*)((const float*)L + e0);
      u16 o[4] = {f2b(v[0]), f2b(v[1]), f2b(v[2]), f2b(v[3])};
      *(uint2*)(Lbf + e0) = *(const uint2*)o;
    } else {
      *(uint2*)(Lbf + e0) = *(const uint2*)((const u16*)L + e0);
    }
  }
}

// ---------------------------------------------------------------------------
// pack kernel (dtype-aware)
// ---------------------------------------------------------------------------
struct PackArgs {
  const void* in[27];
  u16* m0t;     // [256][4096]
  u16* wcat;    // [128][192]
  float* gb;    // [4][32]
  float* wc;    // [3][32]
  const u32* flag;
};

__device__ __forceinline__ float rd_elem(const void* p, size_t idx, u32 mode) {
  return mode ? ((const float*)p)[idx] : b2f(((const u16*)p)[idx]);
}

__global__ __launch_bounds__(256) void pack_k(PackArgs pa) {
  const int bid = blockIdx.x;
  const int t = threadIdx.x;
  const u32 mode = *pa.flag;
  __shared__ u32 lds[256][17];

  if (bid < 128) {
    const int ts = bid >> 4, nc = bid & 15;
    const int xh = ts >> 2, b = ts & 3;
    const void* src = pa.in[xh ? 2 : 0];
    const int node = nc * 256 + t;
    const size_t rbase = ((size_t)b * 4096 + node) * 32;
    if (mode) {
      const f32x4* s4 = (const f32x4*)((const float*)src + rbase);
      u16 tv[32];
      #pragma unroll
      for (int j = 0; j < 8; ++j) {
        f32x4 v = s4[j];
        tv[j * 4] = f2b(v[0]); tv[j * 4 + 1] = f2b(v[1]);
        tv[j * 4 + 2] = f2b(v[2]); tv[j * 4 + 3] = f2b(v[3]);
      }
      #pragma unroll
      for (int i = 0; i < 16; ++i)
        lds[t][i] = (u32)tv[2 * i] | ((u32)tv[2 * i + 1] << 16);
    } else {
      const uint4* s4 = (const uint4*)((const u16*)src + rbase);
      uint4 q0 = s4[0], q1 = s4[1], q2 = s4[2], q3 = s4[3];
      lds[t][0] = q0.x;  lds[t][1] = q0.y;  lds[t][2] = q0.z;  lds[t][3] = q0.w;
      lds[t][4] = q1.x;  lds[t][5] = q1.y;  lds[t][6] = q1.z;  lds[t][7] = q1.w;
      lds[t][8] = q2.x;  lds[t][9] = q2.y;  lds[t][10] = q2.z; lds[t][11] = q2.w;
      lds[t][12] = q3.x; lds[t][13] = q3.y; lds[t][14] = q3.z; lds[t][15] = q3.w;
    }
    __syncthreads();
    const int f = t & 31, sc = t >> 5;
    const int ccol = xh * 128 + b * 32 + f;
    u16 tmp[32];
    #pragma unroll
    for (int i = 0; i < 32; ++i) {
      u32 wv = lds[sc * 32 + i][f >> 1];
      tmp[i] = scrub16((f & 1) ? (u16)(wv >> 16) : (u16)(wv & 0xffffu));
    }
    u16* dst = pa.m0t + (size_t)ccol * 4096 + nc * 256 + sc * 32;
    #pragma unroll
    for (int i = 0; i < 32; i += 8)
      *(uint4*)&dst[i] = *(const uint4*)&tmp[i];
  } else if (bid == 128) {
    const int wxi[4] = {4, 8, 12, 16};
    const int whi[4] = {6, 10, 14, 18};
    for (int e = t; e < 24576; e += 256) {
      int col = e / 192, j = e % 192;
      int g = col >> 5, o = col & 31;
      int a = j >> 5, jj = j & 31;
      const void* Wsrc = (a < 3) ? pa.in[wxi[g]] : pa.in[whi[g]];
      int k = (a < 3) ? a : (a - 3);
      pa.wcat[e] = scrub16(f2b(rd_elem(Wsrc, k * 1024 + jj * 32 + o, mode)));
    }
  } else {
    if (t < 128) {
      const int bx[4] = {5, 9, 13, 17}, bh[4] = {7, 11, 15, 19}, bb[4] = {23, 24, 25, 26};
      int g = t >> 5, o = t & 31;
      pa.gb[t] = scrubf(rd_elem(pa.in[bx[g]], o, mode) + rd_elem(pa.in[bh[g]], o, mode) +
                        rd_elem(pa.in[bb[g]], o, mode));
    } else if (t < 224) {
      int j = t - 128;
      int which = j >> 5, o = j & 31;
      pa.wc[j] = scrubf(rd_elem(pa.in[20 + which], o, mode));
    }
  }
}

// ---------------------------------------------------------------------------
// FAST gemm: PART[split][m][c] = sum_{k in split} A[m][k]*B[c][k]
// A = Lbf [4096][4096] bf16, B [256][4096] bf16.
// grid 1024 = rowTile(64) x colTile(4) x split(4); 256 thr (4 waves 2x2).
// Tile 64x64, BK=64, 16 iters.  Staging: global_load_lds 16B, global chunk
// XOR-swizzled so LDS dest = wave-uniform base + lane*16 (m104-safe) and
// fragment ds_read_b128 hits only 2-way bank conflicts (free, m136).
// ---------------------------------------------------------------------------
__global__ __launch_bounds__(256, 4) void gemm_k(const u16* __restrict__ A,
                                                 const u16* __restrict__ B,
                                                 float* __restrict__ P) {
  __shared__ __align__(16) u16 ldsA[64 * 64];
  __shared__ __align__(16) u16 ldsB[64 * 64];
  const int tid = threadIdx.x;
  const int l = tid & 63;
  const int w = tid >> 6;
  const int rowTile = blockIdx.x & 63;
  const int colTile = (blockIdx.x >> 6) & 3;
  const int split = blockIdx.x >> 8;
  const int wRow = w >> 1, wCol = w & 1;

  f32x4 acc[4];
  #pragma unroll
  for (int i = 0; i < 4; ++i)
    #pragma unroll
    for (int e = 0; e < 4; ++e) acc[i][e] = 0.0f;

  const u16* Abase = A + (size_t)(rowTile * 64) * 4096 + split * 1024;
  const u16* Bbase = B + (size_t)(colTile * 64) * 4096 + split * 1024;

  const int lrow = l >> 3;                 // 0..7 row within 8-row group
  const int gchunk = (l & 7) ^ lrow;       // swizzled global 16B chunk

  for (int it = 0; it < 16; ++it) {
    const int kOff = it * 64;
    #pragma unroll
    for (int j = 0; j < 2; ++j) {
      const int rbase = w * 16 + j * 8;    // wave-uniform
      const int r = rbase + lrow;
      ld_lds16(Abase + (size_t)r * 4096 + kOff + gchunk * 8,
               &ldsA[rbase * 64 + l * 8]);           // byte off = rbase*128 + l*16
      ld_lds16(Bbase + (size_t)r * 4096 + kOff + gchunk * 8,
               &ldsB[rbase * 64 + l * 8]);
    }
    __syncthreads();
    #pragma unroll
    for (int kstep = 0; kstep < 2; ++kstep) {
      const int cg = kstep * 4 + (l >> 4);            // global k-chunk 0..7
      bf16x8 af[2], bf[2];
      #pragma unroll
      for (int mt = 0; mt < 2; ++mt) {
        const int m = wRow * 32 + mt * 16 + (l & 15);
        af[mt] = *(const bf16x8*)&ldsA[m * 64 + (cg ^ (m & 7)) * 8];
      }
      #pragma unroll
      for (int nt = 0; nt < 2; ++nt) {
        const int n = wCol * 32 + nt * 16 + (l & 15);
        bf[nt] = *(const bf16x8*)&ldsB[n * 64 + (cg ^ (n & 7)) * 8];
      }
      #pragma unroll
      for (int mt = 0; mt < 2; ++mt)
        #pragma unroll
        for (int nt = 0; nt < 2; ++nt)
          acc[mt * 2 + nt] =
              __builtin_amdgcn_mfma_f32_16x16x32_bf16(af[mt], bf[nt], acc[mt * 2 + nt], 0, 0, 0);
    }
    __syncthreads();
  }

  float* Pb = P + (size_t)split * 1048576;
  #pragma unroll
  for (int mt = 0; mt < 2; ++mt) {
    const int mBase = rowTile * 64 + wRow * 32 + mt * 16 + (l >> 4) * 4;
    #pragma unroll
    for (int nt = 0; nt < 2; ++nt) {
      const int c = colTile * 64 + wCol * 32 + nt * 16 + (l & 15);
      f32x4 v = acc[mt * 2 + nt];
      #pragma unroll
      for (int reg = 0; reg < 4; ++reg)
        Pb[(size_t)(mBase + reg) * 256 + c] = v[reg];
    }
  }
}

// ---------------------------------------------------------------------------
// reduce: Y1 = sum of 4 split partials; write node-major + transposed
// ---------------------------------------------------------------------------
__global__ __launch_bounds__(256) void reduce_k(const float* __restrict__ P,
                                                u16* __restrict__ Y1T,
                                                u16* __restrict__ Y1N) {
  __shared__ __align__(16) u16 lds[64][266];
  const int t = threadIdx.x;
  const int n0 = blockIdx.x * 64;
  const int nl = t >> 2;
  const int n = n0 + nl;
  const int cb = (t & 3) * 64;
  u16 outv[64];
  for (int cc = 0; cc < 64; cc += 4) {
    const float* p0 = P + (size_t)n * 256 + cb + cc;
    f32x4 s = *(const f32x4*)p0;
    s += *(const f32x4*)(p0 + 1048576);
    s += *(const f32x4*)(p0 + 2 * 1048576);
    s += *(const f32x4*)(p0 + 3 * 1048576);
    outv[cc] = f2b(s[0]); outv[cc + 1] = f2b(s[1]);
    outv[cc + 2] = f2b(s[2]); outv[cc + 3] = f2b(s[3]);
  }
  #pragma unroll
  for (int cc = 0; cc < 64; cc += 8) {
    *(uint4*)&Y1N[(size_t)n * 256 + cb + cc] = *(const uint4*)&outv[cc];
    *(uint4*)&lds[nl][cb + cc] = *(const uint4*)&outv[cc];
  }
  __syncthreads();
  const int c = t;
  u16 col[64];
  for (int i = 0; i < 64; ++i) col[i] = lds[i][c];
  #pragma unroll
  for (int i = 0; i < 64; i += 8)
    *(uint4*)&Y1T[(size_t)c * 4096 + n0 + i] = *(const uint4*)&col[i];
}

// ---------------------------------------------------------------------------
// FAST combine: T2 from PART (fused 2*sum - M0), gates, H/C out (dtype-aware)
// ---------------------------------------------------------------------------
struct CombArgs {
  const void* X; const void* H; const void* C;
  const u16* Y1N; const float* P;
  const u16* WCAT; const float* GB; const float* WC;
  void* OUT;
  const u32* flag;
};

__global__ __launch_bounds__(256) void combine_k(CombArgs a) {
  __shared__ __align__(16) u16 feat[64][200];
  const int t = threadIdx.x;
  const int l = t & 63;
  const int w = t >> 6;
  const int R0 = blockIdx.x * 64;
  const u32 mode = *a.flag;

  {
    const int R = R0 + l;
    const int b = R >> 12, n = R & 4095;
    if (w == 0) {
      if (mode) {
        const f32x4* xs = (const f32x4*)((const float*)a.X + (size_t)R * 32);
        const f32x4* hs = (const f32x4*)((const float*)a.H + (size_t)R * 32);
        u16 tx[32], th[32];
        #pragma unroll
        for (int j = 0; j < 8; ++j) {
          f32x4 vx = xs[j], vh = hs[j];
          tx[j * 4] = f2b(vx[0]); tx[j * 4 + 1] = f2b(vx[1]);
          tx[j * 4 + 2] = f2b(vx[2]); tx[j * 4 + 3] = f2b(vx[3]);
          th[j * 4] = f2b(vh[0]); th[j * 4 + 1] = f2b(vh[1]);
          th[j * 4 + 2] = f2b(vh[2]); th[j * 4 + 3] = f2b(vh[3]);
        }
        #pragma unroll
        for (int i = 0; i < 32; i += 8) {
          *(uint4*)&feat[l][i] = *(const uint4*)&tx[i];
          *(uint4*)&feat[l][96 + i] = *(const uint4*)&th[i];
        }
      } else {
        const uint4* xs = (const uint4*)((const u16*)a.X + (size_t)R * 32);
        *(uint4*)&feat[l][0] = xs[0];  *(uint4*)&feat[l][8] = xs[1];
        *(uint4*)&feat[l][16] = xs[2]; *(uint4*)&feat[l][24] = xs[3];
        const uint4* hs = (const uint4*)((const u16*)a.H + (size_t)R * 32);
        *(uint4*)&feat[l][96] = hs[0];  *(uint4*)&feat[l][104] = hs[1];
        *(uint4*)&feat[l][112] = hs[2]; *(uint4*)&feat[l][120] = hs[3];
      }
    } else if (w == 1) {
      const uint4* t1 = (const uint4*)(a.Y1N + (size_t)n * 256 + b * 32);
      *(uint4*)&feat[l][32] = t1[0]; *(uint4*)&feat[l][40] = t1[1];
      *(uint4*)&feat[l][48] = t1[2]; *(uint4*)&feat[l][56] = t1[3];
      const uint4* t1h = (const uint4*)(a.Y1N + (size_t)n * 256 + 128 + b * 32);
      *(uint4*)&feat[l][128] = t1h[0]; *(uint4*)&feat[l][136] = t1h[1];
      *(uint4*)&feat[l][144] = t1h[2]; *(uint4*)&feat[l][152] = t1h[3];
    } else {
      // T2 = 2 * sum_splits(P) - T0
      const int cOff = (w == 2) ? b * 32 : 128 + b * 32;
      const void* subp = (w == 2) ? a.X : a.H;
      float s[32];
      #pragma unroll
      for (int i = 0; i < 32; ++i) s[i] = 0.0f;
      for (int sp = 0; sp < 4; ++sp) {
        const float* p = a.P + (size_t)sp * 1048576 + (size_t)n * 256 + cOff;
        #pragma unroll
        for (int i = 0; i < 32; i += 4) {
          f32x4 v = *(const f32x4*)(p + i);
          s[i] += v[0]; s[i + 1] += v[1]; s[i + 2] += v[2]; s[i + 3] += v[3];
        }
      }
      u16 outv[32];
      #pragma unroll
      for (int i = 0; i < 32; ++i) {
        const float t0 = rd_elem(subp, (size_t)R * 32 + i, mode);
        outv[i] = f2b(2.0f * s[i] - t0);
      }
      const int seg = (w == 2) ? 64 : 160;
      #pragma unroll
      for (int i = 0; i < 32; i += 8)
        *(uint4*)&feat[l][seg + i] = *(const uint4*)&outv[i];
    }
  }
  __syncthreads();

  f32x4 acc[8];
  #pragma unroll
  for (int i = 0; i < 8; ++i)
    #pragma unroll
    for (int e = 0; e < 4; ++e) acc[i][e] = 0.0f;

  const int rowB = w * 16;
  #pragma unroll
  for (int ks = 0; ks < 6; ++ks) {
    bf16x8 af = *(const bf16x8*)&feat[rowB + (l & 15)][(l >> 4) * 8 + ks * 32];
    #pragma unroll
    for (int ct = 0; ct < 8; ++ct) {
      int ncol = ct * 16 + (l & 15);
      bf16x8 bv = *(const bf16x8*)&a.WCAT[(size_t)ncol * 192 + (l >> 4) * 8 + ks * 32];
      acc[ct] = __builtin_amdgcn_mfma_f32_16x16x32_bf16(af, bv, acc[ct], 0, 0, 0);
    }
  }

  const int o16 = l & 15;
  const int rq = (l >> 4) * 4;
  #pragma unroll
  for (int ctp = 0; ctp < 2; ++ctp) {
    const int o = ctp * 16 + o16;
    const float gbI = a.GB[o], gbF = a.GB[32 + o], gbT = a.GB[64 + o], gbO = a.GB[96 + o];
    const float wci = a.WC[o], wcf = a.WC[32 + o], wco = a.WC[64 + o];
    #pragma unroll
    for (int i = 0; i < 4; ++i) {
      const int R = R0 + w * 16 + rq + i;
      const size_t oidx = (size_t)R * 32 + o;
      const float cold = rd_elem(a.C, oidx, mode);
      const float vI = acc[0 + ctp][i] + gbI + wci * cold;
      const float vF = acc[2 + ctp][i] + gbF + wcf * cold;
      const float vT = acc[4 + ctp][i] + gbT;
      const float vO = acc[6 + ctp][i] + gbO;
      const float I = sigm(vI);
      const float F = sigm(vF);
      const float T = tanh_f(vT);
      const float Cn = F * cold + I * T;
      const float O = sigm(vO + wco * Cn);
      const float Hn = O * tanh_f(Cn);
      if (mode) {
        ((float*)a.OUT)[oidx] = Hn;
        ((float*)a.OUT)[524288 + oidx] = Cn;
      } else {
        ((u16*)a.OUT)[oidx] = f2b(Hn);
        ((u16*)a.OUT)[524288 + oidx] = f2b(Cn);
      }
    }
  }
}

// ===========================================================================
// FALLBACK (R4, proven): 256-block gemm reading L in input dtype
// ===========================================================================
#define LDS_STRIDE 72

__global__ __launch_bounds__(256) void gemm_fb(const void* __restrict__ A,
                                               const u16* __restrict__ B,
                                               const u16* __restrict__ M0T,
                                               u16* __restrict__ outN,
                                               u16* __restrict__ outT,
                                               const u32* __restrict__ flag,
                                               const int emode) {
  __shared__ __align__(16) u16 ldsA[64 * LDS_STRIDE];
  __shared__ __align__(16) u16 ldsB[64 * LDS_STRIDE];
  const int tid = threadIdx.x;
  const int l = tid & 63;
  const int w = tid >> 6;
  const int colTile = blockIdx.x & 3;
  const int rowTile = blockIdx.x >> 2;
  const int wRow = w >> 1, wCol = w & 1;
  const u32 mode = *flag;

  f32x4 acc[4];
  #pragma unroll
  for (int i = 0; i < 4; ++i)
    #pragma unroll
    for (int e = 0; e < 4; ++e) acc[i][e] = 0.0f;

  const size_t Aoff = (size_t)(rowTile * 64) * 4096;
  const u16* Bbase = B + (size_t)(colTile * 64) * 4096;

  const int srow = tid >> 2;
  const int sch = (tid & 3) * 2;

  for (int it = 0; it < 64; ++it) {
    const int kOff = it * 64;
    const size_t aidx = Aoff + (size_t)srow * 4096 + kOff + sch * 8;
    if (mode) {
      const float* Af = (const float*)A + aidx;
      u16 tv[16];
      #pragma unroll
      for (int q = 0; q < 4; ++q) {
        f32x4 v = *(const f32x4*)(Af + q * 4);
        tv[q * 4] = f2b(v[0]); tv[q * 4 + 1] = f2b(v[1]);
        tv[q * 4 + 2] = f2b(v[2]); tv[q * 4 + 3] = f2b(v[3]);
      }
      *(uint4*)&ldsA[srow * LDS_STRIDE + sch * 8] = ((const uint4*)tv)[0];
      *(uint4*)&ldsA[srow * LDS_STRIDE + sch * 8 + 8] = ((const uint4*)tv)[1];
    } else {
      const u16* ga = (const u16*)A + aidx;
      *(uint4*)&ldsA[srow * LDS_STRIDE + sch * 8] = *(const uint4*)ga;
      *(uint4*)&ldsA[srow * LDS_STRIDE + sch * 8 + 8] = *(const uint4*)(ga + 8);
    }
    const u16* gb = Bbase + (size_t)srow * 4096 + kOff + sch * 8;
    *(uint4*)&ldsB[srow * LDS_STRIDE + sch * 8] = *(const uint4*)gb;
    *(uint4*)&ldsB[srow * LDS_STRIDE + sch * 8 + 8] = *(const uint4*)(gb + 8);
    __syncthreads();
    #pragma unroll
    for (int kstep = 0; kstep < 2; ++kstep) {
      const int kb = kstep * 32 + (l >> 4) * 8;
      bf16x8 af[2], bf[2];
      #pragma unroll
      for (int mt = 0; mt < 2; ++mt)
        af[mt] = *(const bf16x8*)&ldsA[(wRow * 32 + mt * 16 + (l & 15)) * LDS_STRIDE + kb];
      #pragma unroll
      for (int nt = 0; nt < 2; ++nt)
        bf[nt] = *(const bf16x8*)&ldsB[(wCol * 32 + nt * 16 + (l & 15)) * LDS_STRIDE + kb];
      #pragma unroll
      for (int mt = 0; mt < 2; ++mt)
        #pragma unroll
        for (int nt = 0; nt < 2; ++nt)
          acc[mt * 2 + nt] =
              __builtin_amdgcn_mfma_f32_16x16x32_bf16(af[mt], bf[nt], acc[mt * 2 + nt], 0, 0, 0);
    }
    __syncthreads();
  }

  if (emode == 0) {
    #pragma unroll
    for (int mt = 0; mt < 2; ++mt) {
      const int mBase = rowTile * 64 + wRow * 32 + mt * 16 + (l >> 4) * 4;
      #pragma unroll
      for (int nt = 0; nt < 2; ++nt) {
        const int c = colTile * 64 + wCol * 32 + nt * 16 + (l & 15);
        f32x4 v = acc[mt * 2 + nt];
        #pragma unroll
        for (int reg = 0; reg < 4; ++reg) {
          const int m = mBase + reg;
          const u16 h = f2b(v[reg]);
          outN[(size_t)m * 256 + c] = h;
          outT[(size_t)c * 4096 + m] = h;
        }
      }
    }
  } else {
    #pragma unroll
    for (int mt = 0; mt < 2; ++mt) {
      const int mBase = rowTile * 64 + wRow * 32 + mt * 16 + (l >> 4) * 4;
      #pragma unroll
      for (int nt = 0; nt < 2; ++nt) {
        const int c = colTile * 64 + wCol * 32 + nt * 16 + (l & 15);
        f32x4 v = acc[mt * 2 + nt];
        #pragma unroll
        for (int reg = 0; reg < 4; ++reg) {
          const int m = mBase + reg;
          const float t0 = b2f(M0T[(size_t)c * 4096 + m]);
          outN[(size_t)m * 256 + c] = f2b(2.0f * v[reg] - t0);
        }
      }
    }
  }
}

struct CombFbArgs {
  const void* X; const void* H; const void* C;
  const u16* Y1N; const u16* T2N;
  const u16* WCAT; const float* GB; const float* WC;
  void* OUT;
  const u32* flag;
};

__global__ __launch_bounds__(256) void combine_fb(CombFbArgs a) {
  __shared__ __align__(16) u16 feat[64][200];
  const int t = threadIdx.x;
  const int l = t & 63;
  const int w = t >> 6;
  const int R0 = blockIdx.x * 64;
  const u32 mode = *a.flag;

  {
    const int R = R0 + l;
    const int b = R >> 12, n = R & 4095;
    if (w == 0) {
      if (mode) {
        const f32x4* xs = (const f32x4*)((const float*)a.X + (size_t)R * 32);
        const f32x4* hs = (const f32x4*)((const float*)a.H + (size_t)R * 32);
        u16 tx[32], th[32];
        #pragma unroll
        for (int j = 0; j < 8; ++j) {
          f32x4 vx = xs[j], vh = hs[j];
          tx[j * 4] = f2b(vx[0]); tx[j * 4 + 1] = f2b(vx[1]);
          tx[j * 4 + 2] = f2b(vx[2]); tx[j * 4 + 3] = f2b(vx[3]);
          th[j * 4] = f2b(vh[0]); th[j * 4 + 1] = f2b(vh[1]);
          th[j * 4 + 2] = f2b(vh[2]); th[j * 4 + 3] = f2b(vh[3]);
        }
        #pragma unroll
        for (int i = 0; i < 32; i += 8) {
          *(uint4*)&feat[l][i] = *(const uint4*)&tx[i];
          *(uint4*)&feat[l][96 + i] = *(const uint4*)&th[i];
        }
      } else {
        const uint4* xs = (const uint4*)((const u16*)a.X + (size_t)R * 32);
        *(uint4*)&feat[l][0] = xs[0];  *(uint4*)&feat[l][8] = xs[1];
        *(uint4*)&feat[l][16] = xs[2]; *(uint4*)&feat[l][24] = xs[3];
        const uint4* hs = (const uint4*)((const u16*)a.H + (size_t)R * 32);
        *(uint4*)&feat[l][96] = hs[0];  *(uint4*)&feat[l][104] = hs[1];
        *(uint4*)&feat[l][112] = hs[2]; *(uint4*)&feat[l][120] = hs[3];
      }
    } else if (w == 1) {
      const uint4* t1 = (const uint4*)(a.Y1N + (size_t)n * 256 + b * 32);
      *(uint4*)&feat[l][32] = t1[0]; *(uint4*)&feat[l][40] = t1[1];
      *(uint4*)&feat[l][48] = t1[2]; *(uint4*)&feat[l][56] = t1[3];
      const uint4* t1h = (const uint4*)(a.Y1N + (size_t)n * 256 + 128 + b * 32);
      *(uint4*)&feat[l][128] = t1h[0]; *(uint4*)&feat[l][136] = t1h[1];
      *(uint4*)&feat[l][144] = t1h[2]; *(uint4*)&feat[l][152] = t1h[3];
    } else if (w == 2) {
      const uint4* t2 = (const uint4*)(a.T2N + (size_t)n * 256 + b * 32);
      *(uint4*)&feat[l][64] = t2[0]; *(uint4*)&feat[l][72] = t2[1];
      *(uint4*)&feat[l][80] = t2[2]; *(uint4*)&feat[l][88] = t2[3];
      const uint4* t2h = (const uint4*)(a.T2N + (size_t)n * 256 + 128 + b * 32);
      *(uint4*)&feat[l][160] = t2h[0]; *(uint4*)&feat[l][168] = t2h[1];
      *(uint4*)&feat[l][176] = t2h[2]; *(uint4*)&feat[l][184] = t2h[3];
    }
  }
  __syncthreads();

  f32x4 acc[8];
  #pragma unroll
  for (int i = 0; i < 8; ++i)
    #pragma unroll
    for (int e = 0; e < 4; ++e) acc[i][e] = 0.0f;

  const int rowB = w * 16;
  #pragma unroll
  for (int ks = 0; ks < 6; ++ks) {
    bf16x8 af = *(const bf16x8*)&feat[rowB + (l & 15)][(l >> 4) * 8 + ks * 32];
    #pragma unroll
    for (int ct = 0; ct < 8; ++ct) {
      int ncol = ct * 16 + (l & 15);
      bf16x8 bv = *(const bf16x8*)&a.WCAT[(size_t)ncol * 192 + (l >> 4) * 8 + ks * 32];
      acc[ct] = __builtin_amdgcn_mfma_f32_16x16x32_bf16(af, bv, acc[ct], 0, 0, 0);
    }
  }

  const int o16 = l & 15;
  const int rq = (l >> 4) * 4;
  #pragma unroll
  for (int ctp = 0; ctp < 2; ++ctp) {
    const int o = ctp * 16 + o16;
    const float gbI = a.GB[o], gbF = a.GB[32 + o], gbT = a.GB[64 + o], gbO = a.GB[96 + o];
    const float wci = a.WC[o], wcf = a.WC[32 + o], wco = a.WC[64 + o];
    #pragma unroll
    for (int i = 0; i < 4; ++i) {
      const int R = R0 + w * 16 + rq + i;
      const size_t oidx = (size_t)R * 32 + o;
      const float cold = rd_elem(a.C, oidx, mode);
      const float vI = acc[0 + ctp][i] + gbI + wci * cold;
      const float vF = acc[2 + ctp][i] + gbF + wcf * cold;
      const float vT = acc[4 + ctp][i] + gbT;
      const float vO = acc[6 + ctp][i] + gbO;
      const float I = sigm(vI);
      const float F = sigm(vF);
      const float T = tanh_f(vT);
      const float Cn = F * cold + I * T;
      const float O = sigm(vO + wco * Cn);
      const float Hn = O * tanh_f(Cn);
      if (mode) {
        ((float*)a.OUT)[oidx] = Hn;
        ((float*)a.OUT)[524288 + oidx] = Cn;
      } else {
        ((u16*)a.OUT)[oidx] = f2b(Hn);
        ((u16*)a.OUT)[524288 + oidx] = f2b(Cn);
      }
    }
  }
}

// ---------------------------------------------------------------------------
// launcher
// ---------------------------------------------------------------------------
extern "C" void kernel_launch(void* const* d_in, const int* in_sizes, int n_in,
                              void* d_out, int out_size, void* d_ws, size_t ws_size,
                              hipStream_t stream) {
  char* ws = (char*)d_ws;
  const bool fast = ws_size >= (size_t)FWS_TOTAL;

  if (fast) {
    u16* M0T = (u16*)(ws + FWS_M0T);
    u16* Y1T = (u16*)(ws + FWS_Y1T);
    u16* Y1N = (u16*)(ws + FWS_Y1N);
    u16* WCAT = (u16*)(ws + FWS_WCAT);
    float* GB = (float*)(ws + FWS_GB);
    float* WC = (float*)(ws + FWS_WC);
    u32* FLAG = (u32*)(ws + FWS_FLAG);
    u16* LBF = (u16*)(ws + FWS_LBF);
    float* PART = (float*)(ws + FWS_PART);

    flag_k<<<1, 64, 0, stream>>>((const u16*)d_in[1], FLAG);
    convL_k<<<2048, 256, 0, stream>>>(d_in[1], LBF, FLAG);

    PackArgs pa;
    for (int i = 0; i < 27; ++i) pa.in[i] = d_in[i];
    pa.m0t = M0T; pa.wcat = WCAT; pa.gb = GB; pa.wc = WC; pa.flag = FLAG;
    pack_k<<<130, 256, 0, stream>>>(pa);

    gemm_k<<<1024, 256, 0, stream>>>(LBF, M0T, PART);
    reduce_k<<<64, 256, 0, stream>>>(PART, Y1T, Y1N);
    gemm_k<<<1024, 256, 0, stream>>>(LBF, Y1T, PART);

    CombArgs ca;
    ca.X = d_in[0]; ca.H = d_in[2]; ca.C = d_in[3];
    ca.Y1N = Y1N; ca.P = PART; ca.WCAT = WCAT; ca.GB = GB; ca.WC = WC;
    ca.OUT = d_out; ca.flag = FLAG;
    combine_k<<<256, 256, 0, stream>>>(ca);
  } else {
    u16* M0T = (u16*)(ws + BWS_M0T);
    u16* Y1T = (u16*)(ws + BWS_Y1T);
    u16* Y1N = (u16*)(ws + BWS_Y1N);
    u16* T2N = (u16*)(ws + BWS_T2N);
    u16* WCAT = (u16*)(ws + BWS_WCAT);
    float* GB = (float*)(ws + BWS_GB);
    float* WC = (float*)(ws + BWS_WC);
    u32* FLAG = (u32*)(ws + BWS_FLAG);

    flag_k<<<1, 64, 0, stream>>>((const u16*)d_in[1], FLAG);

    PackArgs pa;
    for (int i = 0; i < 27; ++i) pa.in[i] = d_in[i];
    pa.m0t = M0T; pa.wcat = WCAT; pa.gb = GB; pa.wc = WC; pa.flag = FLAG;
    pack_k<<<130, 256, 0, stream>>>(pa);

    gemm_fb<<<256, 256, 0, stream>>>(d_in[1], M0T, nullptr, Y1N, Y1T, FLAG, 0);
    gemm_fb<<<256, 256, 0, stream>>>(d_in[1], Y1T, M0T, T2N, nullptr, FLAG, 1);

    CombFbArgs ca;
    ca.X = d_in[0]; ca.H = d_in[2]; ca.C = d_in[3];
    ca.Y1N = Y1N; ca.T2N = T2N; ca.WCAT = WCAT; ca.GB = GB; ca.WC = WC;
    ca.OUT = d_out; ca.flag = FLAG;
    combine_fb<<<256, 256, 0, stream>>>(ca);
  }
}

// Round 6
// 213.122 us; speedup vs baseline: 1.6929x; 1.2224x over previous
//
#include <hip/hip_runtime.h>

// ---------------------------------------------------------------------------
// GConvLSTM cell, B=4, N=4096, CI=CO=32, K=3.  Inputs/outputs f32 (runtime-
// detected via flag_k; bf16 fallback retained).  Internal compute bf16 MFMA.
//
// R6: pack_k WCAT stage parallelized 1 block -> 96 blocks (R5 profile: one
// latency-serialized block made pack_k the 41.5 us top dispatch).  reduce_k
// grid 64 -> 256 blocks.
//
// Fast path (ws >= 58.7 MB):
//   0) flag_k:   detect input dtype
//   1) convL_k:  L -> Lbf bf16 [4096][4096]
//   2) pack_k:   M0T[256][4096] = [X|H]^T, WcatT[128][192], biases
//   3) gemm_k:   PART[4][4096][256] f32 = split-K(4) partials of L @ M0
//   4) reduce_k: Y1N + Y1T bf16 = sum partials
//   5) gemm_k:   PART = split-K partials of L @ Y1
//   6) combine_k: feats @ WcatT -> gates -> H,C  (T2 = 2*sum(PART) - M0 fused)
// ---------------------------------------------------------------------------

typedef __bf16 bf16x8 __attribute__((ext_vector_type(8)));
typedef float f32x4 __attribute__((ext_vector_type(4)));

typedef unsigned short u16;
typedef unsigned int u32;

__device__ __forceinline__ float b2f(u16 h) {
  u32 u = ((u32)h) << 16;
  return __builtin_bit_cast(float, u);
}
__device__ __forceinline__ u16 f2b(float f) {
  u32 u = __builtin_bit_cast(u32, f);
  u += 0x7fffu + ((u >> 16) & 1u);   // round-to-nearest-even
  return (u16)(u >> 16);
}
__device__ __forceinline__ u16 scrub16(u16 h) {
  return ((u16)(h & 0x7fffu) > (u16)0x7f80u) ? (u16)0 : h;
}
__device__ __forceinline__ float scrubf(float f) { return (f == f) ? f : 0.0f; }
__device__ __forceinline__ float sigm(float x) { return 1.0f / (1.0f + __expf(-x)); }
__device__ __forceinline__ float tanh_f(float x) { return 1.0f - 2.0f / (__expf(2.0f * x) + 1.0f); }

#define AS1 __attribute__((address_space(1)))
#define AS3 __attribute__((address_space(3)))
__device__ __forceinline__ void ld_lds16(const void* g, void* l) {
  __builtin_amdgcn_global_load_lds((const AS1 void*)g, (AS3 void*)l, 16, 0, 0);
}

// ---------------------------------------------------------------------------
// Workspace layouts (bytes)
// ---------------------------------------------------------------------------
#define FWS_M0T   0u
#define FWS_Y1T   2097152u
#define FWS_Y1N   4194304u
#define FWS_WCAT  6291456u
#define FWS_GB    6340608u
#define FWS_WC    6341120u
#define FWS_FLAG  6341632u
#define FWS_LBF   8388608u
#define FWS_PART  41943040u
#define FWS_TOTAL 58720256u
// fallback (R4) layout
#define BWS_M0T   0u
#define BWS_Y1T   2097152u
#define BWS_Y1N   4194304u
#define BWS_T2N   6291456u
#define BWS_WCAT  8388608u
#define BWS_GB    8437760u
#define BWS_WC    8438272u
#define BWS_FLAG  8438784u

// ---------------------------------------------------------------------------
// dtype-detect: scan first 1024 u16 words of L.
// ---------------------------------------------------------------------------
__global__ __launch_bounds__(64) void flag_k(const u16* __restrict__ L,
                                             u32* __restrict__ flag) {
  __shared__ int cnt;
  if (threadIdx.x == 0) cnt = 0;
  __syncthreads();
  int c = 0;
  for (int i = threadIdx.x; i < 1024; i += 64) {
    int e = (L[i] >> 7) & 0xFF;
    if (e >= 96 && e <= 126) ++c;
  }
  atomicAdd(&cnt, c);
  __syncthreads();
  if (threadIdx.x == 0) *flag = (cnt < 870) ? 1u : 0u;
}

// ---------------------------------------------------------------------------
// convL: L (f32 or bf16) -> Lbf bf16.
// ---------------------------------------------------------------------------
__global__ __launch_bounds__(256) void convL_k(const void* __restrict__ L,
                                               u16* __restrict__ Lbf,
                                               const u32* __restrict__ flag) {
  const u32 mode = *flag;
  const int gtid = blockIdx.x * 256 + threadIdx.x;     // 0..524287
  #pragma unroll
  for (int it = 0; it < 8; ++it) {
    const size_t e0 = ((size_t)it * 524288 + gtid) * 4;
    if (mode) {
      f32x4 v = *(const f32x4*)((const float*)L + e0);
      u16 o[4] = {f2b(v[0]), f2b(v[1]), f2b(v[2]), f2b(v[3])};
      *(uint2*)(Lbf + e0) = *(const uint2*)o;
    } else {
      *(uint2*)(Lbf + e0) = *(const uint2*)((const u16*)L + e0);
    }
  }
}

// ---------------------------------------------------------------------------
// pack kernel (dtype-aware).  Grid 225:
//   bid 0..127   : X/H transpose -> M0T
//   bid 128..223 : WCAT, 1 element per thread (R6: was 1 block x 96 iters)
//   bid 224      : biases + peepholes
// ---------------------------------------------------------------------------
struct PackArgs {
  const void* in[27];
  u16* m0t;     // [256][4096]
  u16* wcat;    // [128][192]
  float* gb;    // [4][32]
  float* wc;    // [3][32]
  const u32* flag;
};

__device__ __forceinline__ float rd_elem(const void* p, size_t idx, u32 mode) {
  return mode ? ((const float*)p)[idx] : b2f(((const u16*)p)[idx]);
}

__global__ __launch_bounds__(256) void pack_k(PackArgs pa) {
  const int bid = blockIdx.x;
  const int t = threadIdx.x;
  const u32 mode = *pa.flag;
  __shared__ u32 lds[256][17];

  if (bid < 128) {
    const int ts = bid >> 4, nc = bid & 15;
    const int xh = ts >> 2, b = ts & 3;
    const void* src = pa.in[xh ? 2 : 0];
    const int node = nc * 256 + t;
    const size_t rbase = ((size_t)b * 4096 + node) * 32;
    if (mode) {
      const f32x4* s4 = (const f32x4*)((const float*)src + rbase);
      u16 tv[32];
      #pragma unroll
      for (int j = 0; j < 8; ++j) {
        f32x4 v = s4[j];
        tv[j * 4] = f2b(v[0]); tv[j * 4 + 1] = f2b(v[1]);
        tv[j * 4 + 2] = f2b(v[2]); tv[j * 4 + 3] = f2b(v[3]);
      }
      #pragma unroll
      for (int i = 0; i < 16; ++i)
        lds[t][i] = (u32)tv[2 * i] | ((u32)tv[2 * i + 1] << 16);
    } else {
      const uint4* s4 = (const uint4*)((const u16*)src + rbase);
      uint4 q0 = s4[0], q1 = s4[1], q2 = s4[2], q3 = s4[3];
      lds[t][0] = q0.x;  lds[t][1] = q0.y;  lds[t][2] = q0.z;  lds[t][3] = q0.w;
      lds[t][4] = q1.x;  lds[t][5] = q1.y;  lds[t][6] = q1.z;  lds[t][7] = q1.w;
      lds[t][8] = q2.x;  lds[t][9] = q2.y;  lds[t][10] = q2.z; lds[t][11] = q2.w;
      lds[t][12] = q3.x; lds[t][13] = q3.y; lds[t][14] = q3.z; lds[t][15] = q3.w;
    }
    __syncthreads();
    const int f = t & 31, sc = t >> 5;
    const int ccol = xh * 128 + b * 32 + f;
    u16 tmp[32];
    #pragma unroll
    for (int i = 0; i < 32; ++i) {
      u32 wv = lds[sc * 32 + i][f >> 1];
      tmp[i] = scrub16((f & 1) ? (u16)(wv >> 16) : (u16)(wv & 0xffffu));
    }
    u16* dst = pa.m0t + (size_t)ccol * 4096 + nc * 256 + sc * 32;
    #pragma unroll
    for (int i = 0; i < 32; i += 8)
      *(uint4*)&dst[i] = *(const uint4*)&tmp[i];
  } else if (bid < 224) {
    // WCAT: 96 blocks x 256 threads = 24576 elements, one each.
    const int wxi[4] = {4, 8, 12, 16};
    const int whi[4] = {6, 10, 14, 18};
    const int e = (bid - 128) * 256 + t;
    const int col = e / 192, j = e % 192;
    const int g = col >> 5, o = col & 31;
    const int a = j >> 5, jj = j & 31;
    const void* Wsrc = (a < 3) ? pa.in[wxi[g]] : pa.in[whi[g]];
    const int k = (a < 3) ? a : (a - 3);
    pa.wcat[e] = scrub16(f2b(rd_elem(Wsrc, k * 1024 + jj * 32 + o, mode)));
  } else {
    if (t < 128) {
      const int bx[4] = {5, 9, 13, 17}, bh[4] = {7, 11, 15, 19}, bb[4] = {23, 24, 25, 26};
      int g = t >> 5, o = t & 31;
      pa.gb[t] = scrubf(rd_elem(pa.in[bx[g]], o, mode) + rd_elem(pa.in[bh[g]], o, mode) +
                        rd_elem(pa.in[bb[g]], o, mode));
    } else if (t < 224) {
      int j = t - 128;
      int which = j >> 5, o = j & 31;
      pa.wc[j] = scrubf(rd_elem(pa.in[20 + which], o, mode));
    }
  }
}

// ---------------------------------------------------------------------------
// FAST gemm: PART[split][m][c] = sum_{k in split} A[m][k]*B[c][k]
// grid 1024 = rowTile(64) x colTile(4) x split(4); 256 thr (4 waves 2x2).
// Tile 64x64, BK=64.  global_load_lds 16B with XOR swizzle.
// ---------------------------------------------------------------------------
__global__ __launch_bounds__(256, 4) void gemm_k(const u16* __restrict__ A,
                                                 const u16* __restrict__ B,
                                                 float* __restrict__ P) {
  __shared__ __align__(16) u16 ldsA[64 * 64];
  __shared__ __align__(16) u16 ldsB[64 * 64];
  const int tid = threadIdx.x;
  const int l = tid & 63;
  const int w = tid >> 6;
  const int rowTile = blockIdx.x & 63;
  const int colTile = (blockIdx.x >> 6) & 3;
  const int split = blockIdx.x >> 8;
  const int wRow = w >> 1, wCol = w & 1;

  f32x4 acc[4];
  #pragma unroll
  for (int i = 0; i < 4; ++i)
    #pragma unroll
    for (int e = 0; e < 4; ++e) acc[i][e] = 0.0f;

  const u16* Abase = A + (size_t)(rowTile * 64) * 4096 + split * 1024;
  const u16* Bbase = B + (size_t)(colTile * 64) * 4096 + split * 1024;

  const int lrow = l >> 3;
  const int gchunk = (l & 7) ^ lrow;

  for (int it = 0; it < 16; ++it) {
    const int kOff = it * 64;
    #pragma unroll
    for (int j = 0; j < 2; ++j) {
      const int rbase = w * 16 + j * 8;
      const int r = rbase + lrow;
      ld_lds16(Abase + (size_t)r * 4096 + kOff + gchunk * 8,
               &ldsA[rbase * 64 + l * 8]);
      ld_lds16(Bbase + (size_t)r * 4096 + kOff + gchunk * 8,
               &ldsB[rbase * 64 + l * 8]);
    }
    __syncthreads();
    #pragma unroll
    for (int kstep = 0; kstep < 2; ++kstep) {
      const int cg = kstep * 4 + (l >> 4);
      bf16x8 af[2], bf[2];
      #pragma unroll
      for (int mt = 0; mt < 2; ++mt) {
        const int m = wRow * 32 + mt * 16 + (l & 15);
        af[mt] = *(const bf16x8*)&ldsA[m * 64 + (cg ^ (m & 7)) * 8];
      }
      #pragma unroll
      for (int nt = 0; nt < 2; ++nt) {
        const int n = wCol * 32 + nt * 16 + (l & 15);
        bf[nt] = *(const bf16x8*)&ldsB[n * 64 + (cg ^ (n & 7)) * 8];
      }
      #pragma unroll
      for (int mt = 0; mt < 2; ++mt)
        #pragma unroll
        for (int nt = 0; nt < 2; ++nt)
          acc[mt * 2 + nt] =
              __builtin_amdgcn_mfma_f32_16x16x32_bf16(af[mt], bf[nt], acc[mt * 2 + nt], 0, 0, 0);
    }
    __syncthreads();
  }

  float* Pb = P + (size_t)split * 1048576;
  #pragma unroll
  for (int mt = 0; mt < 2; ++mt) {
    const int mBase = rowTile * 64 + wRow * 32 + mt * 16 + (l >> 4) * 4;
    #pragma unroll
    for (int nt = 0; nt < 2; ++nt) {
      const int c = colTile * 64 + wCol * 32 + nt * 16 + (l & 15);
      f32x4 v = acc[mt * 2 + nt];
      #pragma unroll
      for (int reg = 0; reg < 4; ++reg)
        Pb[(size_t)(mBase + reg) * 256 + c] = v[reg];
    }
  }
}

// ---------------------------------------------------------------------------
// reduce: Y1 = sum of 4 split partials; node-major + transposed outputs.
// R6: grid 256 blocks (16 nodes each) for occupancy.
// ---------------------------------------------------------------------------
__global__ __launch_bounds__(256) void reduce_k(const float* __restrict__ P,
                                                u16* __restrict__ Y1T,
                                                u16* __restrict__ Y1N) {
  __shared__ __align__(16) u16 lds[16][264];
  const int t = threadIdx.x;
  const int n0 = blockIdx.x * 16;
  const int nl = t >> 4;               // 0..15
  const int n = n0 + nl;
  const int cb = (t & 15) * 16;        // 16 cols per thread
  u16 outv[16];
  #pragma unroll
  for (int cc = 0; cc < 16; cc += 4) {
    const float* p0 = P + (size_t)n * 256 + cb + cc;
    f32x4 s = *(const f32x4*)p0;
    s += *(const f32x4*)(p0 + 1048576);
    s += *(const f32x4*)(p0 + 2 * 1048576);
    s += *(const f32x4*)(p0 + 3 * 1048576);
    outv[cc] = f2b(s[0]); outv[cc + 1] = f2b(s[1]);
    outv[cc + 2] = f2b(s[2]); outv[cc + 3] = f2b(s[3]);
  }
  #pragma unroll
  for (int cc = 0; cc < 16; cc += 8) {
    *(uint4*)&Y1N[(size_t)n * 256 + cb + cc] = *(const uint4*)&outv[cc];
    *(uint4*)&lds[nl][cb + cc] = *(const uint4*)&outv[cc];
  }
  __syncthreads();
  const int c = t;
  u16 col[16];
  #pragma unroll
  for (int i = 0; i < 16; ++i) col[i] = lds[i][c];
  #pragma unroll
  for (int i = 0; i < 16; i += 8)
    *(uint4*)&Y1T[(size_t)c * 4096 + n0 + i] = *(const uint4*)&col[i];
}

// ---------------------------------------------------------------------------
// FAST combine
// ---------------------------------------------------------------------------
struct CombArgs {
  const void* X; const void* H; const void* C;
  const u16* Y1N; const float* P;
  const u16* WCAT; const float* GB; const float* WC;
  void* OUT;
  const u32* flag;
};

__global__ __launch_bounds__(256) void combine_k(CombArgs a) {
  __shared__ __align__(16) u16 feat[64][200];
  const int t = threadIdx.x;
  const int l = t & 63;
  const int w = t >> 6;
  const int R0 = blockIdx.x * 64;
  const u32 mode = *a.flag;

  {
    const int R = R0 + l;
    const int b = R >> 12, n = R & 4095;
    if (w == 0) {
      if (mode) {
        const f32x4* xs = (const f32x4*)((const float*)a.X + (size_t)R * 32);
        const f32x4* hs = (const f32x4*)((const float*)a.H + (size_t)R * 32);
        u16 tx[32], th[32];
        #pragma unroll
        for (int j = 0; j < 8; ++j) {
          f32x4 vx = xs[j], vh = hs[j];
          tx[j * 4] = f2b(vx[0]); tx[j * 4 + 1] = f2b(vx[1]);
          tx[j * 4 + 2] = f2b(vx[2]); tx[j * 4 + 3] = f2b(vx[3]);
          th[j * 4] = f2b(vh[0]); th[j * 4 + 1] = f2b(vh[1]);
          th[j * 4 + 2] = f2b(vh[2]); th[j * 4 + 3] = f2b(vh[3]);
        }
        #pragma unroll
        for (int i = 0; i < 32; i += 8) {
          *(uint4*)&feat[l][i] = *(const uint4*)&tx[i];
          *(uint4*)&feat[l][96 + i] = *(const uint4*)&th[i];
        }
      } else {
        const uint4* xs = (const uint4*)((const u16*)a.X + (size_t)R * 32);
        *(uint4*)&feat[l][0] = xs[0];  *(uint4*)&feat[l][8] = xs[1];
        *(uint4*)&feat[l][16] = xs[2]; *(uint4*)&feat[l][24] = xs[3];
        const uint4* hs = (const uint4*)((const u16*)a.H + (size_t)R * 32);
        *(uint4*)&feat[l][96] = hs[0];  *(uint4*)&feat[l][104] = hs[1];
        *(uint4*)&feat[l][112] = hs[2]; *(uint4*)&feat[l][120] = hs[3];
      }
    } else if (w == 1) {
      const uint4* t1 = (const uint4*)(a.Y1N + (size_t)n * 256 + b * 32);
      *(uint4*)&feat[l][32] = t1[0]; *(uint4*)&feat[l][40] = t1[1];
      *(uint4*)&feat[l][48] = t1[2]; *(uint4*)&feat[l][56] = t1[3];
      const uint4* t1h = (const uint4*)(a.Y1N + (size_t)n * 256 + 128 + b * 32);
      *(uint4*)&feat[l][128] = t1h[0]; *(uint4*)&feat[l][136] = t1h[1];
      *(uint4*)&feat[l][144] = t1h[2]; *(uint4*)&feat[l][152] = t1h[3];
    } else {
      const int cOff = (w == 2) ? b * 32 : 128 + b * 32;
      const void* subp = (w == 2) ? a.X : a.H;
      float s[32];
      #pragma unroll
      for (int i = 0; i < 32; ++i) s[i] = 0.0f;
      for (int sp = 0; sp < 4; ++sp) {
        const float* p = a.P + (size_t)sp * 1048576 + (size_t)n * 256 + cOff;
        #pragma unroll
        for (int i = 0; i < 32; i += 4) {
          f32x4 v = *(const f32x4*)(p + i);
          s[i] += v[0]; s[i + 1] += v[1]; s[i + 2] += v[2]; s[i + 3] += v[3];
        }
      }
      u16 outv[32];
      #pragma unroll
      for (int i = 0; i < 32; ++i) {
        const float t0 = rd_elem(subp, (size_t)R * 32 + i, mode);
        outv[i] = f2b(2.0f * s[i] - t0);
      }
      const int seg = (w == 2) ? 64 : 160;
      #pragma unroll
      for (int i = 0; i < 32; i += 8)
        *(uint4*)&feat[l][seg + i] = *(const uint4*)&outv[i];
    }
  }
  __syncthreads();

  f32x4 acc[8];
  #pragma unroll
  for (int i = 0; i < 8; ++i)
    #pragma unroll
    for (int e = 0; e < 4; ++e) acc[i][e] = 0.0f;

  const int rowB = w * 16;
  #pragma unroll
  for (int ks = 0; ks < 6; ++ks) {
    bf16x8 af = *(const bf16x8*)&feat[rowB + (l & 15)][(l >> 4) * 8 + ks * 32];
    #pragma unroll
    for (int ct = 0; ct < 8; ++ct) {
      int ncol = ct * 16 + (l & 15);
      bf16x8 bv = *(const bf16x8*)&a.WCAT[(size_t)ncol * 192 + (l >> 4) * 8 + ks * 32];
      acc[ct] = __builtin_amdgcn_mfma_f32_16x16x32_bf16(af, bv, acc[ct], 0, 0, 0);
    }
  }

  const int o16 = l & 15;
  const int rq = (l >> 4) * 4;
  #pragma unroll
  for (int ctp = 0; ctp < 2; ++ctp) {
    const int o = ctp * 16 + o16;
    const float gbI = a.GB[o], gbF = a.GB[32 + o], gbT = a.GB[64 + o], gbO = a.GB[96 + o];
    const float wci = a.WC[o], wcf = a.WC[32 + o], wco = a.WC[64 + o];
    #pragma unroll
    for (int i = 0; i < 4; ++i) {
      const int R = R0 + w * 16 + rq + i;
      const size_t oidx = (size_t)R * 32 + o;
      const float cold = rd_elem(a.C, oidx, mode);
      const float vI = acc[0 + ctp][i] + gbI + wci * cold;
      const float vF = acc[2 + ctp][i] + gbF + wcf * cold;
      const float vT = acc[4 + ctp][i] + gbT;
      const float vO = acc[6 + ctp][i] + gbO;
      const float I = sigm(vI);
      const float F = sigm(vF);
      const float T = tanh_f(vT);
      const float Cn = F * cold + I * T;
      const float O = sigm(vO + wco * Cn);
      const float Hn = O * tanh_f(Cn);
      if (mode) {
        ((float*)a.OUT)[oidx] = Hn;
        ((float*)a.OUT)[524288 + oidx] = Cn;
      } else {
        ((u16*)a.OUT)[oidx] = f2b(Hn);
        ((u16*)a.OUT)[524288 + oidx] = f2b(Cn);
      }
    }
  }
}

// ===========================================================================
// FALLBACK (R4, proven): 256-block gemm reading L in input dtype
// ===========================================================================
#define LDS_STRIDE 72

__global__ __launch_bounds__(256) void gemm_fb(const void* __restrict__ A,
                                               const u16* __restrict__ B,
                                               const u16* __restrict__ M0T,
                                               u16* __restrict__ outN,
                                               u16* __restrict__ outT,
                                               const u32* __restrict__ flag,
                                               const int emode) {
  __shared__ __align__(16) u16 ldsA[64 * LDS_STRIDE];
  __shared__ __align__(16) u16 ldsB[64 * LDS_STRIDE];
  const int tid = threadIdx.x;
  const int l = tid & 63;
  const int w = tid >> 6;
  const int colTile = blockIdx.x & 3;
  const int rowTile = blockIdx.x >> 2;
  const int wRow = w >> 1, wCol = w & 1;
  const u32 mode = *flag;

  f32x4 acc[4];
  #pragma unroll
  for (int i = 0; i < 4; ++i)
    #pragma unroll
    for (int e = 0; e < 4; ++e) acc[i][e] = 0.0f;

  const size_t Aoff = (size_t)(rowTile * 64) * 4096;
  const u16* Bbase = B + (size_t)(colTile * 64) * 4096;

  const int srow = tid >> 2;
  const int sch = (tid & 3) * 2;

  for (int it = 0; it < 64; ++it) {
    const int kOff = it * 64;
    const size_t aidx = Aoff + (size_t)srow * 4096 + kOff + sch * 8;
    if (mode) {
      const float* Af = (const float*)A + aidx;
      u16 tv[16];
      #pragma unroll
      for (int q = 0; q < 4; ++q) {
        f32x4 v = *(const f32x4*)(Af + q * 4);
        tv[q * 4] = f2b(v[0]); tv[q * 4 + 1] = f2b(v[1]);
        tv[q * 4 + 2] = f2b(v[2]); tv[q * 4 + 3] = f2b(v[3]);
      }
      *(uint4*)&ldsA[srow * LDS_STRIDE + sch * 8] = ((const uint4*)tv)[0];
      *(uint4*)&ldsA[srow * LDS_STRIDE + sch * 8 + 8] = ((const uint4*)tv)[1];
    } else {
      const u16* ga = (const u16*)A + aidx;
      *(uint4*)&ldsA[srow * LDS_STRIDE + sch * 8] = *(const uint4*)ga;
      *(uint4*)&ldsA[srow * LDS_STRIDE + sch * 8 + 8] = *(const uint4*)(ga + 8);
    }
    const u16* gb = Bbase + (size_t)srow * 4096 + kOff + sch * 8;
    *(uint4*)&ldsB[srow * LDS_STRIDE + sch * 8] = *(const uint4*)gb;
    *(uint4*)&ldsB[srow * LDS_STRIDE + sch * 8 + 8] = *(const uint4*)(gb + 8);
    __syncthreads();
    #pragma unroll
    for (int kstep = 0; kstep < 2; ++kstep) {
      const int kb = kstep * 32 + (l >> 4) * 8;
      bf16x8 af[2], bf[2];
      #pragma unroll
      for (int mt = 0; mt < 2; ++mt)
        af[mt] = *(const bf16x8*)&ldsA[(wRow * 32 + mt * 16 + (l & 15)) * LDS_STRIDE + kb];
      #pragma unroll
      for (int nt = 0; nt < 2; ++nt)
        bf[nt] = *(const bf16x8*)&ldsB[(wCol * 32 + nt * 16 + (l & 15)) * LDS_STRIDE + kb];
      #pragma unroll
      for (int mt = 0; mt < 2; ++mt)
        #pragma unroll
        for (int nt = 0; nt < 2; ++nt)
          acc[mt * 2 + nt] =
              __builtin_amdgcn_mfma_f32_16x16x32_bf16(af[mt], bf[nt], acc[mt * 2 + nt], 0, 0, 0);
    }
    __syncthreads();
  }

  if (emode == 0) {
    #pragma unroll
    for (int mt = 0; mt < 2; ++mt) {
      const int mBase = rowTile * 64 + wRow * 32 + mt * 16 + (l >> 4) * 4;
      #pragma unroll
      for (int nt = 0; nt < 2; ++nt) {
        const int c = colTile * 64 + wCol * 32 + nt * 16 + (l & 15);
        f32x4 v = acc[mt * 2 + nt];
        #pragma unroll
        for (int reg = 0; reg < 4; ++reg) {
          const int m = mBase + reg;
          const u16 h = f2b(v[reg]);
          outN[(size_t)m * 256 + c] = h;
          outT[(size_t)c * 4096 + m] = h;
        }
      }
    }
  } else {
    #pragma unroll
    for (int mt = 0; mt < 2; ++mt) {
      const int mBase = rowTile * 64 + wRow * 32 + mt * 16 + (l >> 4) * 4;
      #pragma unroll
      for (int nt = 0; nt < 2; ++nt) {
        const int c = colTile * 64 + wCol * 32 + nt * 16 + (l & 15);
        f32x4 v = acc[mt * 2 + nt];
        #pragma unroll
        for (int reg = 0; reg < 4; ++reg) {
          const int m = mBase + reg;
          const float t0 = b2f(M0T[(size_t)c * 4096 + m]);
          outN[(size_t)m * 256 + c] = f2b(2.0f * v[reg] - t0);
        }
      }
    }
  }
}

struct CombFbArgs {
  const void* X; const void* H; const void* C;
  const u16* Y1N; const u16* T2N;
  const u16* WCAT; const float* GB; const float* WC;
  void* OUT;
  const u32* flag;
};

__global__ __launch_bounds__(256) void combine_fb(CombFbArgs a) {
  __shared__ __align__(16) u16 feat[64][200];
  const int t = threadIdx.x;
  const int l = t & 63;
  const int w = t >> 6;
  const int R0 = blockIdx.x * 64;
  const u32 mode = *a.flag;

  {
    const int R = R0 + l;
    const int b = R >> 12, n = R & 4095;
    if (w == 0) {
      if (mode) {
        const f32x4* xs = (const f32x4*)((const float*)a.X + (size_t)R * 32);
        const f32x4* hs = (const f32x4*)((const float*)a.H + (size_t)R * 32);
        u16 tx[32], th[32];
        #pragma unroll
        for (int j = 0; j < 8; ++j) {
          f32x4 vx = xs[j], vh = hs[j];
          tx[j * 4] = f2b(vx[0]); tx[j * 4 + 1] = f2b(vx[1]);
          tx[j * 4 + 2] = f2b(vx[2]); tx[j * 4 + 3] = f2b(vx[3]);
          th[j * 4] = f2b(vh[0]); th[j * 4 + 1] = f2b(vh[1]);
          th[j * 4 + 2] = f2b(vh[2]); th[j * 4 + 3] = f2b(vh[3]);
        }
        #pragma unroll
        for (int i = 0; i < 32; i += 8) {
          *(uint4*)&feat[l][i] = *(const uint4*)&tx[i];
          *(uint4*)&feat[l][96 + i] = *(const uint4*)&th[i];
        }
      } else {
        const uint4* xs = (const uint4*)((const u16*)a.X + (size_t)R * 32);
        *(uint4*)&feat[l][0] = xs[0];  *(uint4*)&feat[l][8] = xs[1];
        *(uint4*)&feat[l][16] = xs[2]; *(uint4*)&feat[l][24] = xs[3];
        const uint4* hs = (const uint4*)((const u16*)a.H + (size_t)R * 32);
        *(uint4*)&feat[l][96] = hs[0];  *(uint4*)&feat[l][104] = hs[1];
        *(uint4*)&feat[l][112] = hs[2]; *(uint4*)&feat[l][120] = hs[3];
      }
    } else if (w == 1) {
      const uint4* t1 = (const uint4*)(a.Y1N + (size_t)n * 256 + b * 32);
      *(uint4*)&feat[l][32] = t1[0]; *(uint4*)&feat[l][40] = t1[1];
      *(uint4*)&feat[l][48] = t1[2]; *(uint4*)&feat[l][56] = t1[3];
      const uint4* t1h = (const uint4*)(a.Y1N + (size_t)n * 256 + 128 + b * 32);
      *(uint4*)&feat[l][128] = t1h[0]; *(uint4*)&feat[l][136] = t1h[1];
      *(uint4*)&feat[l][144] = t1h[2]; *(uint4*)&feat[l][152] = t1h[3];
    } else if (w == 2) {
      const uint4* t2 = (const uint4*)(a.T2N + (size_t)n * 256 + b * 32);
      *(uint4*)&feat[l][64] = t2[0]; *(uint4*)&feat[l][72] = t2[1];
      *(uint4*)&feat[l][80] = t2[2]; *(uint4*)&feat[l][88] = t2[3];
      const uint4* t2h = (const uint4*)(a.T2N + (size_t)n * 256 + 128 + b * 32);
      *(uint4*)&feat[l][160] = t2h[0]; *(uint4*)&feat[l][168] = t2h[1];
      *(uint4*)&feat[l][176] = t2h[2]; *(uint4*)&feat[l][184] = t2h[3];
    }
  }
  __syncthreads();

  f32x4 acc[8];
  #pragma unroll
  for (int i = 0; i < 8; ++i)
    #pragma unroll
    for (int e = 0; e < 4; ++e) acc[i][e] = 0.0f;

  const int rowB = w * 16;
  #pragma unroll
  for (int ks = 0; ks < 6; ++ks) {
    bf16x8 af = *(const bf16x8*)&feat[rowB + (l & 15)][(l >> 4) * 8 + ks * 32];
    #pragma unroll
    for (int ct = 0; ct < 8; ++ct) {
      int ncol = ct * 16 + (l & 15);
      bf16x8 bv = *(const bf16x8*)&a.WCAT[(size_t)ncol * 192 + (l >> 4) * 8 + ks * 32];
      acc[ct] = __builtin_amdgcn_mfma_f32_16x16x32_bf16(af, bv, acc[ct], 0, 0, 0);
    }
  }

  const int o16 = l & 15;
  const int rq = (l >> 4) * 4;
  #pragma unroll
  for (int ctp = 0; ctp < 2; ++ctp) {
    const int o = ctp * 16 + o16;
    const float gbI = a.GB[o], gbF = a.GB[32 + o], gbT = a.GB[64 + o], gbO = a.GB[96 + o];
    const float wci = a.WC[o], wcf = a.WC[32 + o], wco = a.WC[64 + o];
    #pragma unroll
    for (int i = 0; i < 4; ++i) {
      const int R = R0 + w * 16 + rq + i;
      const size_t oidx = (size_t)R * 32 + o;
      const float cold = rd_elem(a.C, oidx, mode);
      const float vI = acc[0 + ctp][i] + gbI + wci * cold;
      const float vF = acc[2 + ctp][i] + gbF + wcf * cold;
      const float vT = acc[4 + ctp][i] + gbT;
      const float vO = acc[6 + ctp][i] + gbO;
      const float I = sigm(vI);
      const float F = sigm(vF);
      const float T = tanh_f(vT);
      const float Cn = F * cold + I * T;
      const float O = sigm(vO + wco * Cn);
      const float Hn = O * tanh_f(Cn);
      if (mode) {
        ((float*)a.OUT)[oidx] = Hn;
        ((float*)a.OUT)[524288 + oidx] = Cn;
      } else {
        ((u16*)a.OUT)[oidx] = f2b(Hn);
        ((u16*)a.OUT)[524288 + oidx] = f2b(Cn);
      }
    }
  }
}

// ---------------------------------------------------------------------------
// launcher
// ---------------------------------------------------------------------------
extern "C" void kernel_launch(void* const* d_in, const int* in_sizes, int n_in,
                              void* d_out, int out_size, void* d_ws, size_t ws_size,
                              hipStream_t stream) {
  char* ws = (char*)d_ws;
  const bool fast = ws_size >= (size_t)FWS_TOTAL;

  if (fast) {
    u16* M0T = (u16*)(ws + FWS_M0T);
    u16* Y1T = (u16*)(ws + FWS_Y1T);
    u16* Y1N = (u16*)(ws + FWS_Y1N);
    u16* WCAT = (u16*)(ws + FWS_WCAT);
    float* GB = (float*)(ws + FWS_GB);
    float* WC = (float*)(ws + FWS_WC);
    u32* FLAG = (u32*)(ws + FWS_FLAG);
    u16* LBF = (u16*)(ws + FWS_LBF);
    float* PART = (float*)(ws + FWS_PART);

    flag_k<<<1, 64, 0, stream>>>((const u16*)d_in[1], FLAG);
    convL_k<<<2048, 256, 0, stream>>>(d_in[1], LBF, FLAG);

    PackArgs pa;
    for (int i = 0; i < 27; ++i) pa.in[i] = d_in[i];
    pa.m0t = M0T; pa.wcat = WCAT; pa.gb = GB; pa.wc = WC; pa.flag = FLAG;
    pack_k<<<225, 256, 0, stream>>>(pa);

    gemm_k<<<1024, 256, 0, stream>>>(LBF, M0T, PART);
    reduce_k<<<256, 256, 0, stream>>>(PART, Y1T, Y1N);
    gemm_k<<<1024, 256, 0, stream>>>(LBF, Y1T, PART);

    CombArgs ca;
    ca.X = d_in[0]; ca.H = d_in[2]; ca.C = d_in[3];
    ca.Y1N = Y1N; ca.P = PART; ca.WCAT = WCAT; ca.GB = GB; ca.WC = WC;
    ca.OUT = d_out; ca.flag = FLAG;
    combine_k<<<256, 256, 0, stream>>>(ca);
  } else {
    u16* M0T = (u16*)(ws + BWS_M0T);
    u16* Y1T = (u16*)(ws + BWS_Y1T);
    u16* Y1N = (u16*)(ws + BWS_Y1N);
    u16* T2N = (u16*)(ws + BWS_T2N);
    u16* WCAT = (u16*)(ws + BWS_WCAT);
    float* GB = (float*)(ws + BWS_GB);
    float* WC = (float*)(ws + BWS_WC);
    u32* FLAG = (u32*)(ws + BWS_FLAG);

    flag_k<<<1, 64, 0, stream>>>((const u16*)d_in[1], FLAG);

    PackArgs pa;
    for (int i = 0; i < 27; ++i) pa.in[i] = d_in[i];
    pa.m0t = M0T; pa.wcat = WCAT; pa.gb = GB; pa.wc = WC; pa.flag = FLAG;
    pack_k<<<225, 256, 0, stream>>>(pa);

    gemm_fb<<<256, 256, 0, stream>>>(d_in[1], M0T, nullptr, Y1N, Y1T, FLAG, 0);
    gemm_fb<<<256, 256, 0, stream>>>(d_in[1], Y1T, M0T, T2N, nullptr, FLAG, 1);

    CombFbArgs ca;
    ca.X = d_in[0]; ca.H = d_in[2]; ca.C = d_in[3];
    ca.Y1N = Y1N; ca.T2N = T2N; ca.WCAT = WCAT; ca.GB = GB; ca.WC = WC;
    ca.OUT = d_out; ca.flag = FLAG;
    combine_fb<<<225 == 0 ? 1 : 256, 256, 0, stream>>>(ca);
  }
}